// Round 1
// baseline (186.560 us; speedup 1.0000x reference)
//
#include <hip/hip_runtime.h>

#define SEQ    512
#define BATCH  1024
#define NTAG   54
#define TSTART 52
#define TSTOP  53
#define NEGINF (-10000.0f)
#define NW     4   // waves (batch elements) per block

// ---------------------------------------------------------------------------
// Kernel 1: per-batch forward recursion + gold score.
// wave = one batch element, lane = tag index j (lanes 54..63 padded).
// alpha_new[j] = log( sum_i E[j,i]*a[i] ) + m + mrow[j] + feat[j]
//   E[j,i] = exp(trans[j,i]-mrow[j])  -- constant, held in 56 VGPRs/lane
//   a[i]   = exp(alpha[i]-m),  m = max(alpha[0], alpha[START])  (see theory)
// ---------------------------------------------------------------------------

#define STEP(S, FV, TG, MK) do {                                              \
    float m_ = fmaxf(__shfl(alpha, 0), __shfl(alpha, TSTART));                \
    float aj_ = (lane < NTAG) ? __expf(alpha - m_) : 0.f;                     \
    alds[wv][lane] = aj_;                                                     \
    asm volatile("" ::: "memory");                                            \
    float ac0 = 0.f, ac1 = 0.f, ac2 = 0.f, ac3 = 0.f;                         \
    const float4* ap_ = (const float4*)(&alds[wv][0]);                        \
    _Pragma("unroll")                                                         \
    for (int g_ = 0; g_ < 14; ++g_) {                                         \
        float4 av_ = ap_[g_];                                                 \
        ac0 = fmaf(Ereg[4*g_+0], av_.x, ac0);                                 \
        ac1 = fmaf(Ereg[4*g_+1], av_.y, ac1);                                 \
        ac2 = fmaf(Ereg[4*g_+2], av_.z, ac2);                                 \
        ac3 = fmaf(Ereg[4*g_+3], av_.w, ac3);                                 \
    }                                                                         \
    float ss_ = (ac0 + ac1) + (ac2 + ac3);                                    \
    float na_ = __logf(ss_) + m_ + mrow + (FV);                               \
    alpha = (((MK) > 0) && (lane < NTAG)) ? na_ : alpha;                      \
    float emit_ = __shfl((FV), (TG));                                         \
    float trv_  = tlds[(TG) * NTAG + prev];                                   \
    float mf_   = ((S) == 0) ? 1.0f : (float)(MK);                            \
    gold  = fmaf(trv_ + emit_, mf_, gold);                                    \
    msumv += (MK);                                                            \
    prev = (TG);                                                              \
} while (0)

__global__ __launch_bounds__(64 * NW) void crf_fwd_kernel(
    const float* __restrict__ em, const float* __restrict__ tr,
    const int* __restrict__ tags, const int* __restrict__ mask,
    float* __restrict__ part, int* __restrict__ msum)
{
    __shared__ float tlds[NTAG * NTAG];
    __shared__ __align__(16) float alds[NW][64];

    const int tid = threadIdx.x;
    for (int k = tid; k < NTAG * NTAG; k += 64 * NW) tlds[k] = tr[k];
    __syncthreads();

    const int wv   = tid >> 6;
    const int lane = tid & 63;
    const int b    = blockIdx.x * NW + wv;

    // --- E row (56 regs, fully unrolled so it stays in VGPRs) ---
    float Ereg[56];
    #pragma unroll
    for (int i = 0; i < 56; ++i)
        Ereg[i] = (lane < NTAG && i < NTAG) ? tlds[lane * NTAG + i] : -1e30f;
    float mrow = -1e30f;
    #pragma unroll
    for (int i = 0; i < 56; ++i) mrow = fmaxf(mrow, Ereg[i]);
    #pragma unroll
    for (int i = 0; i < 56; ++i)
        Ereg[i] = (lane < NTAG && i < NTAG) ? __expf(Ereg[i] - mrow) : 0.f;
    if (lane >= NTAG) mrow = 0.f;

    // --- state ---
    float alpha = (lane == TSTART) ? 0.f : NEGINF;
    float gold  = 0.f;
    int   prev  = TSTART;
    int   msumv = 0;

    const size_t bT = (size_t)b * NTAG;
    #define LDF(S) ((lane < NTAG) ? em[((size_t)(S) * BATCH) * NTAG + bT + lane] : 0.f)
    #define LDT(S) (tags[(S) * BATCH + b])
    #define LDM(S) (mask[(S) * BATCH + b])

    // 4-deep prefetch pipeline (static register slots; loop unrolled x4)
    float f0 = LDF(0), f1 = LDF(1), f2 = LDF(2), f3 = LDF(3);
    int   t0 = LDT(0), t1 = LDT(1), t2 = LDT(2), t3 = LDT(3);
    int   k0 = LDM(0), k1 = LDM(1), k2 = LDM(2), k3 = LDM(3);

    for (int sb = 0; sb < SEQ; sb += 4) {
        STEP(sb + 0, f0, t0, k0);
        { int sn = (sb + 4 < SEQ) ? sb + 4 : SEQ - 1; f0 = LDF(sn); t0 = LDT(sn); k0 = LDM(sn); }
        STEP(sb + 1, f1, t1, k1);
        { int sn = (sb + 5 < SEQ) ? sb + 5 : SEQ - 1; f1 = LDF(sn); t1 = LDT(sn); k1 = LDM(sn); }
        STEP(sb + 2, f2, t2, k2);
        { int sn = (sb + 6 < SEQ) ? sb + 6 : SEQ - 1; f2 = LDF(sn); t2 = LDT(sn); k2 = LDM(sn); }
        STEP(sb + 3, f3, t3, k3);
        { int sn = (sb + 7 < SEQ) ? sb + 7 : SEQ - 1; f3 = LDF(sn); t3 = LDT(sn); k3 = LDM(sn); }
    }

    // --- final forward score: exact logsumexp over lanes ---
    float af = (lane < NTAG) ? alpha + tlds[TSTOP * NTAG + lane] : -1e30f;
    float mx = af;
    #pragma unroll
    for (int off = 32; off >= 1; off >>= 1) mx = fmaxf(mx, __shfl_xor(mx, off));
    float ex = (lane < NTAG) ? __expf(af - mx) : 0.f;
    #pragma unroll
    for (int off = 32; off >= 1; off >>= 1) ex += __shfl_xor(ex, off);
    float fwd = __logf(ex) + mx;

    // --- gold: stop transition from tags[length-1] ---
    int li   = (msumv > 0) ? (msumv - 1) : 0;
    int ltag = tags[li * BATCH + b];
    gold += tlds[TSTOP * NTAG + ltag];

    if (lane == 0) { part[b] = fwd - gold; msum[b] = msumv; }
    #undef LDF
    #undef LDT
    #undef LDM
}

// ---------------------------------------------------------------------------
// Kernel 2: deterministic reduction  out = sum(part) / sum(msum)
// ---------------------------------------------------------------------------
__global__ __launch_bounds__(256) void crf_reduce_kernel(
    const float* __restrict__ part, const int* __restrict__ msum,
    float* __restrict__ out)
{
    const int tid = threadIdx.x;
    float s = 0.f;
    int   m = 0;
    for (int k = tid; k < BATCH; k += 256) { s += part[k]; m += msum[k]; }
    #pragma unroll
    for (int off = 32; off >= 1; off >>= 1) {
        s += __shfl_xor(s, off);
        m += __shfl_xor(m, off);
    }
    __shared__ float sl[4];
    __shared__ int   ml[4];
    if ((tid & 63) == 0) { sl[tid >> 6] = s; ml[tid >> 6] = m; }
    __syncthreads();
    if (tid == 0)
        out[0] = (sl[0] + sl[1] + sl[2] + sl[3]) /
                 (float)(ml[0] + ml[1] + ml[2] + ml[3]);
}

extern "C" void kernel_launch(void* const* d_in, const int* in_sizes, int n_in,
                              void* d_out, int out_size, void* d_ws, size_t ws_size,
                              hipStream_t stream)
{
    const float* em   = (const float*)d_in[0];
    const float* tr   = (const float*)d_in[1];
    const int*   tags = (const int*)d_in[2];
    const int*   mask = (const int*)d_in[3];

    float* part = (float*)d_ws;
    int*   msum = (int*)((char*)d_ws + BATCH * sizeof(float));
    float* out  = (float*)d_out;

    crf_fwd_kernel<<<BATCH / NW, 64 * NW, 0, stream>>>(em, tr, tags, mask, part, msum);
    crf_reduce_kernel<<<1, 256, 0, stream>>>(part, msum, out);
}